// Round 15
// baseline (311.576 us; speedup 1.0000x reference)
//
#include <hip/hip_runtime.h>

typedef unsigned short u16;
typedef __attribute__((ext_vector_type(4))) unsigned short us4;
typedef __attribute__((ext_vector_type(8))) unsigned short us8;
typedef __attribute__((ext_vector_type(8))) __bf16 bf16x8;
typedef __attribute__((ext_vector_type(4))) float f32x4;
typedef __attribute__((ext_vector_type(16))) float f32x16;

#define L2E 1.4426950408889634f
#define RSQ128 0.08838834764831845f

__device__ __forceinline__ u16 f2b(float f) {
  unsigned u = __builtin_bit_cast(unsigned, f);
  u += 0x7fffu + ((u >> 16) & 1u);          // round-to-nearest-even
  return (u16)(u >> 16);
}
__device__ __forceinline__ float b2f(u16 s) {
  unsigned u = ((unsigned)s) << 16;
  return __builtin_bit_cast(float, u);
}

__device__ __forceinline__ void gload16(const u16* g, const u16* l) {
  __builtin_amdgcn_global_load_lds(
      (const __attribute__((address_space(1))) unsigned*)g,
      (__attribute__((address_space(3))) unsigned*)l, 16, 0, 0);
}

// ---------------------------------------------------------------------------
// Fused f32->bf16 convert for x, qkv_w, out_w AND DFT-table init, one launch.
// ---------------------------------------------------------------------------
__global__ __launch_bounds__(256)
void convert_init(const float* __restrict__ x, const float* __restrict__ w1,
                  const float* __restrict__ w2,
                  u16* __restrict__ dx, u16* __restrict__ dw1, u16* __restrict__ dw2,
                  u16* __restrict__ Fm, u16* __restrict__ Cm)
{
  const int bi = blockIdx.x;
  if (bi >= 12288) {
    const int i = (bi - 12288) * 256 + threadIdx.x;
    const float w0 = 6.283185307179586f / 128.f;
    if (i < 144 * 128) {
      const int fc = i >> 7, d = i & 127;
      float v = 0.f;
      if (fc < 130) {
        const int f = fc >> 1;
        const float ang = (float)((f * d) & 127) * w0;
        v = ((fc & 1) == 0 ? cosf(ang) : -sinf(ang)) * RSQ128;
      }
      Fm[i] = f2b(v);
    } else {
      const int j = i - 144 * 128;
      const int t = j / 160, fc = j % 160;
      float v = 0.f;
      if (fc < 130) {
        const int f = fc >> 1;
        if ((fc & 1) == 0) {
          if (f == 0)       v = RSQ128;
          else if (f == 64) v = (t & 1) ? -RSQ128 : RSQ128;
          else              v = 2.f * cosf((float)((f * t) & 127) * w0) * RSQ128;
        } else {
          if (f != 0 && f != 64)
            v = -2.f * sinf((float)((f * t) & 127) * w0) * RSQ128;
        }
      }
      Cm[j] = f2b(v);
    }
    return;
  }
  const float* src; u16* dst; long off;
  if (bi < 4096)        { src = x;  dst = dx;  off = (long)bi * 2048; }
  else if (bi < 10240)  { src = w1; dst = dw1; off = (long)(bi - 4096) * 2048; }
  else                  { src = w2; dst = dw2; off = (long)(bi - 10240) * 2048; }
  const long i = off + threadIdx.x * 8;
  float4 a = *(const float4*)(src + i);
  float4 b = *(const float4*)(src + i + 4);
  us8 o = { f2b(a.x), f2b(a.y), f2b(a.z), f2b(a.w),
            f2b(b.x), f2b(b.y), f2b(b.z), f2b(b.w) };
  *(us8*)(dst + i) = o;
}

// ---------------------------------------------------------------------------
// bf16 TN GEMM, m97 structure + 32x32x16 MFMA (half the MFMA instructions of
// the 16x16x32 version per BK=64 step, same ds_read bytes; 32x32 ubench rate
// 2382 vs 2075 TF). C/D layout: col=lane&31, row=(reg&3)+8*(reg>>2)+
// 4*(lane>>5) [HW-verified m74/m101]. A/B intra-K mapping assumed identical
// for both operands -> any k-permutation cancels. Staging/swizzle unchanged.
// MODE 0: RoPE + scatter to per-head q/k/v. MODE 1: plain f32 store.
// ---------------------------------------------------------------------------
template<int MODE>
__global__ __launch_bounds__(256, 4)
void gemm_bf16(const u16* __restrict__ A, const u16* __restrict__ Bm,
               float* __restrict__ Cout,
               u16* __restrict__ qb, u16* __restrict__ kb, u16* __restrict__ vb,
               const float* __restrict__ cosT, const float* __restrict__ sinT,
               int M, int N, int K)
{
  __shared__ u16 As[128 * 64];
  __shared__ u16 Bs[128 * 64];
  const int tid  = threadIdx.x;
  const int lane = tid & 63;
  const int wid  = tid >> 6;
  const int c5   = lane & 31;
  const int h5   = lane >> 5;

  const int cpx  = gridDim.x >> 3;        // tiles per XCD
  const int ntx  = N >> 7;
  const int mpx  = cpx / ntx;             // m-panels per XCD
  const int xcd  = blockIdx.x & 7;
  const int t    = blockIdx.x >> 3;
  const int m0 = (xcd * mpx + (t % mpx)) * 128;
  const int n0 = (t / mpx) * 128;
  const int wm = (wid >> 1) * 64;
  const int wn = (wid & 1) * 64;

  f32x16 acc[2][2];
#pragma unroll
  for (int i = 0; i < 2; ++i)
#pragma unroll
    for (int j = 0; j < 2; ++j) acc[i][j] = (f32x16)0.f;

  // staging (identical to proven BK=64): inverse-swizzled global col-block,
  // linear LDS dest for global_load_lds
  const int sr8 = lane >> 3;
  const int scb = (lane & 7) ^ sr8;
  const u16* Ag = A  + (long)(m0 + wid * 32 + sr8) * K + scb * 8;
  const u16* Bg = Bm + (long)(n0 + wid * 32 + sr8) * K + scb * 8;

  // fragment rows (row&7 == lane&7 for all four fragments)
  const int ar0 = (wm + c5) * 64,      ar1 = (wm + 32 + c5) * 64;
  const int br0 = (wn + c5) * 64,      br1 = (wn + 32 + c5) * 64;
  const int l7  = lane & 7;

  for (int k0 = 0; k0 < K; k0 += 64) {
#pragma unroll
    for (int u = 0; u < 4; ++u) {
      gload16(Ag + (long)(u * 8) * K + k0, &As[(wid * 32 + u * 8) * 64]);
      gload16(Bg + (long)(u * 8) * K + k0, &Bs[(wid * 32 + u * 8) * 64]);
    }
    __syncthreads();
#pragma unroll
    for (int ks = 0; ks < 4; ++ks) {
      const int kx = ((ks * 2 + h5) ^ l7) << 3;   // swizzled 16B block
      bf16x8 a0 = *(const bf16x8*)(As + ar0 + kx);
      bf16x8 a1 = *(const bf16x8*)(As + ar1 + kx);
      bf16x8 b0 = *(const bf16x8*)(Bs + br0 + kx);
      bf16x8 b1 = *(const bf16x8*)(Bs + br1 + kx);
      acc[0][0] = __builtin_amdgcn_mfma_f32_32x32x16_bf16(a0, b0, acc[0][0], 0, 0, 0);
      acc[0][1] = __builtin_amdgcn_mfma_f32_32x32x16_bf16(a0, b1, acc[0][1], 0, 0, 0);
      acc[1][0] = __builtin_amdgcn_mfma_f32_32x32x16_bf16(a1, b0, acc[1][0], 0, 0, 0);
      acc[1][1] = __builtin_amdgcn_mfma_f32_32x32x16_bf16(a1, b1, acc[1][1], 0, 0, 0);
    }
    __syncthreads();
  }

  if (MODE == 0) {
    const int w  = n0 >> 11;
    const int hh = (n0 >> 7) & 15;
#pragma unroll
    for (int mt = 0; mt < 2; ++mt) {
      const int rowbase = m0 + wm + mt * 32 + 4 * h5;
#pragma unroll
      for (int nt = 0; nt < 2; ++nt) {
        const int d = wn + nt * 32 + c5;
#pragma unroll
        for (int reg = 0; reg < 16; ++reg) {
          float val = acc[mt][nt][reg];
          float oth = __shfl_xor(val, 1);   // RoPE partner d^1 (adjacent lane)
          const int tok = rowbase + (reg & 3) + 8 * (reg >> 2);
          const int s   = tok & 2047;
          const long idx = ((long)(((tok >> 11) << 4) | hh) * 2048 + s) * 128 + d;
          if (w == 2) {
            vb[idx] = f2b(val);
          } else {
            float cc = cosT[s * 64 + (d >> 1)];
            float sn = sinT[s * 64 + (d >> 1)];
            float res = (d & 1) ? (oth * sn + val * cc) : (val * cc - oth * sn);
            ((w == 0) ? qb : kb)[idx] = f2b(res);
          }
        }
      }
    }
  } else {
#pragma unroll
    for (int mt = 0; mt < 2; ++mt) {
      const int rowbase = m0 + wm + mt * 32 + 4 * h5;
#pragma unroll
      for (int nt = 0; nt < 2; ++nt) {
        const int col = n0 + wn + nt * 32 + c5;
#pragma unroll
        for (int reg = 0; reg < 16; ++reg) {
          const int row = rowbase + (reg & 3) + 8 * (reg >> 2);
          Cout[(long)row * N + col] = acc[mt][nt][reg];
        }
      }
    }
  }
}

// ---------------------------------------------------------------------------
// FUSED holographic path (proven round 12).
// ---------------------------------------------------------------------------
__global__ __launch_bounds__(512, 1)
void holo_fused(const u16* __restrict__ qb, const u16* __restrict__ kb,
                const u16* __restrict__ vb, const u16* __restrict__ Fm,
                const u16* __restrict__ Cm, u16* __restrict__ hb16)
{
  __shared__ u16 Cs[128 * 168];
  __shared__ u16 Un[128 * 168];
  u16* const Fs = Un;
  u16* const Ps = Un;
  const int tid = threadIdx.x, lane = tid & 63, wv = tid >> 6;
  const int c = lane & 15, g = lane >> 4;
  const long row0 = (long)blockIdx.x * 128;

  for (int i = tid; i < 144 * 16; i += 512) {
    const int fc = i >> 4, d8 = (i & 15) << 3;
    us8 v = *(const us8*)(Fm + fc * 128 + d8);
    *(us8*)((char*)Fs + ((fc * 256 + d8 * 2) ^ ((fc & 7) << 4))) = v;
  }
  for (int i = tid; i < 128 * 20; i += 512) {
    const int tr = i / 20, c8 = (i % 20) * 8;
    *(us8*)(Cs + tr * 168 + c8) = *(const us8*)(Cm + tr * 160 + c8);
  }

  const long ar = row0 + wv * 16 + c;
  bf16x8 aq[4], ak[4], av[4];
#pragma unroll
  for (int ks = 0; ks < 4; ++ks) {
    aq[ks] = *(const bf16x8*)(qb + ar * 128 + 32 * ks + 8 * g);
    ak[ks] = *(const bf16x8*)(kb + ar * 128 + 32 * ks + 8 * g);
    av[ks] = *(const bf16x8*)(vb + ar * 128 + 32 * ks + 8 * g);
  }
  __syncthreads();

  f32x4 accq[9], acck[9], accv[9];
#pragma unroll
  for (int nt = 0; nt < 9; ++nt) {
    accq[nt] = (f32x4)0.f; acck[nt] = (f32x4)0.f; accv[nt] = (f32x4)0.f;
  }
#pragma unroll
  for (int nt = 0; nt < 9; ++nt) {
    const int fc = nt * 16 + c;
    const int sw = (fc & 7) << 4;
#pragma unroll
    for (int ks = 0; ks < 4; ++ks) {
      bf16x8 bf = *(const bf16x8*)((char*)Fs + ((fc * 256 + (32 * ks + 8 * g) * 2) ^ sw));
      accq[nt] = __builtin_amdgcn_mfma_f32_16x16x32_bf16(aq[ks], bf, accq[nt], 0, 0, 0);
      acck[nt] = __builtin_amdgcn_mfma_f32_16x16x32_bf16(ak[ks], bf, acck[nt], 0, 0, 0);
      accv[nt] = __builtin_amdgcn_mfma_f32_16x16x32_bf16(av[ks], bf, accv[nt], 0, 0, 0);
    }
  }
  __syncthreads();

  const bool even = ((c & 1) == 0);
  const int lr = wv * 16 + 4 * g;
#pragma unroll
  for (int nt = 0; nt < 9; ++nt) {
#pragma unroll
    for (int r = 0; r < 4; ++r) {
      float q = accq[nt][r], k = acck[nt][r], v = accv[nt][r];
      float xq = __shfl_xor(q, 1), xk = __shfl_xor(k, 1), xv = __shfl_xor(v, 1);
      float bc = even ? (k * v - xk * xv) : (xk * v + k * xv);
      float xbc = __shfl_xor(bc, 1);
      float p = even ? (q * bc + xq * xbc) : (xq * bc - q * xbc);
      Ps[(lr + r) * 168 + nt * 16 + c] = f2b(p);
    }
  }
  {
    const int zr = tid >> 2, zc = 144 + (tid & 3) * 4;
    us4 z = {0, 0, 0, 0};
    *(us4*)(Ps + zr * 168 + zc) = z;
  }
  __syncthreads();

  f32x4 acc2[8];
#pragma unroll
  for (int i = 0; i < 8; ++i) acc2[i] = (f32x4)0.f;
#pragma unroll
  for (int ks = 0; ks < 5; ++ks) {
    bf16x8 pa = *(const bf16x8*)(Ps + (wv * 16 + c) * 168 + ks * 32 + 8 * g);
#pragma unroll
    for (int nt2 = 0; nt2 < 8; ++nt2) {
      bf16x8 cb = *(const bf16x8*)(Cs + (nt2 * 16 + c) * 168 + ks * 32 + 8 * g);
      acc2[nt2] = __builtin_amdgcn_mfma_f32_16x16x32_bf16(pa, cb, acc2[nt2], 0, 0, 0);
    }
  }
#pragma unroll
  for (int nt2 = 0; nt2 < 8; ++nt2) {
#pragma unroll
    for (int r = 0; r < 4; ++r) {
      const int row = (int)row0 + wv * 16 + 4 * g + r;
      const int bh = row >> 11, s = row & 2047;
      const long addr = ((long)(((bh >> 4) << 11) | s) << 11) + ((bh & 15) << 7) + nt2 * 16 + c;
      hb16[addr] = f2b(acc2[nt2][r]);
    }
  }
}

// ---------------------------------------------------------------------------
// Causal flash attention v6 + defer-max (proven round 12).
// ---------------------------------------------------------------------------
__global__ __launch_bounds__(256, 2)
void flash_attn(const u16* __restrict__ qb, const u16* __restrict__ kb,
                const u16* __restrict__ vb, u16* __restrict__ ab16)
{
  __shared__ u16 Ks[2][64 * 128];
  __shared__ u16 Vs[128 * 72];
  __shared__ u16 Ps[64 * 72];
  const int tid  = threadIdx.x;
  const int lane = tid & 63;
  const int wv   = tid >> 6;      // 0..3
  const int c    = lane & 15;
  const int g    = lane >> 4;
  const int bh = blockIdx.x;
  const int zz = blockIdx.y;      // 0..15
  const long basek = (long)bh * 2048 * 128;
  const int b = bh >> 4, hh = bh & 15;
  const u16* kbb = kb + basek;
  const u16* vbb = vb + basek;

  int kr[4], kc[4];
#pragma unroll
  for (int u = 0; u < 4; ++u) {
    kr[u] = 16 * u + 4 * wv + (lane >> 4);
    kc[u] = ((lane & 15) ^ (kr[u] & 7)) * 8;
  }
  const int vkp = tid & 31;
  const int vdb = (tid >> 5) * 16;

  for (int ph = 0; ph < 2; ++ph) {
    const int qt = ph ? (31 - zz) : zz;
    const int q0 = qt * 64;

    bf16x8 qf[4];
    {
      const u16* qptr = qb + basek + (long)(q0 + wv * 16 + c) * 128 + 8 * g;
#pragma unroll
      for (int ks = 0; ks < 4; ++ks) qf[ks] = *(const bf16x8*)(qptr + 32 * ks);
    }
    f32x4 acco[8];
#pragma unroll
    for (int i = 0; i < 8; ++i) acco[i] = (f32x4)0.f;
    float m = -1e30f, l = 0.f;

    {
#pragma unroll
      for (int u = 0; u < 4; ++u)
        gload16(kbb + (long)kr[u] * 128 + kc[u], &Ks[0][(16 * u + 4 * wv) * 128]);
      const u16* vp = vbb + (long)(2 * vkp) * 128 + vdb;
      us8 v0a = *(const us8*)vp;
      us8 v0b = *(const us8*)(vp + 8);
      us8 v1a = *(const us8*)(vp + 128);
      us8 v1b = *(const us8*)(vp + 136);
      __syncthreads();
#pragma unroll
      for (int j = 0; j < 8; ++j) {
        *(unsigned*)(&Vs[(vdb + j) * 72 + 2 * vkp]) =
            (unsigned)v0a[j] | ((unsigned)v1a[j] << 16);
        *(unsigned*)(&Vs[(vdb + 8 + j) * 72 + 2 * vkp]) =
            (unsigned)v0b[j] | ((unsigned)v1b[j] << 16);
      }
      __syncthreads();
    }

    int cur = 0;
    for (int t = 0; t <= qt; ++t) {
      const int nxt = cur ^ 1;
      const bool more = (t < qt);
      us8 v0a, v0b, v1a, v1b;
      if (more) {
        const int kv1 = (t + 1) * 64;
#pragma unroll
        for (int u = 0; u < 4; ++u)
          gload16(kbb + (long)(kv1 + kr[u]) * 128 + kc[u],
                  &Ks[nxt][(16 * u + 4 * wv) * 128]);
        const u16* vp = vbb + (long)(kv1 + 2 * vkp) * 128 + vdb;
        v0a = *(const us8*)vp;
        v0b = *(const us8*)(vp + 8);
        v1a = *(const us8*)(vp + 128);
        v1b = *(const us8*)(vp + 136);
      }

      const int kv0 = t * 64;
      f32x4 accs[4];
#pragma unroll
      for (int i = 0; i < 4; ++i) accs[i] = (f32x4)0.f;
#pragma unroll
      for (int ni = 0; ni < 4; ++ni) {
        const int krow = ni * 16 + c;
#pragma unroll
        for (int ks = 0; ks < 4; ++ks) {
          bf16x8 kf = *(const bf16x8*)(&Ks[cur][krow * 128 + (((4 * ks + g) ^ (krow & 7)) * 8)]);
          accs[ni] = __builtin_amdgcn_mfma_f32_16x16x32_bf16(kf, qf[ks], accs[ni], 0, 0, 0);
        }
      }

      const int qrow = q0 + wv * 16 + c;
      float sv[4][4];
      float tmax = -1e30f;
      const bool maskt = (t == qt);
#pragma unroll
      for (int ni = 0; ni < 4; ++ni)
#pragma unroll
        for (int r = 0; r < 4; ++r) {
          float s = accs[ni][r] * RSQ128;
          if (maskt && (kv0 + ni * 16 + 4 * g + r > qrow)) s = -1e30f;
          sv[ni][r] = s;
          tmax = fmaxf(tmax, s);
        }
      tmax = fmaxf(tmax, __shfl_xor(tmax, 16));
      tmax = fmaxf(tmax, __shfl_xor(tmax, 32));
      const bool needr = !__all(tmax <= m);
      const float mn = needr ? fmaxf(m, tmax) : m;
      float ps = 0.f;
#pragma unroll
      for (int ni = 0; ni < 4; ++ni) {
        us4 pk;
#pragma unroll
        for (int r = 0; r < 4; ++r) {
          float p = exp2f((sv[ni][r] - mn) * L2E);
          ps += p;
          pk[r] = f2b(p);
        }
        *(us4*)(&Ps[(wv * 16 + c) * 72 + ni * 16 + 4 * g]) = pk;
      }
      ps += __shfl_xor(ps, 16);
      ps += __shfl_xor(ps, 32);
      if (needr) {                      // wave-uniform branch
        const float alpha = exp2f((m - mn) * L2E);
        m = mn;
        l = l * alpha + ps;
        float ar[4];
#pragma unroll
        for (int r = 0; r < 4; ++r) ar[r] = __shfl(alpha, 4 * g + r);
#pragma unroll
        for (int i = 0; i < 8; ++i)
#pragma unroll
          for (int r = 0; r < 4; ++r) acco[i][r] *= ar[r];
      } else {
        l += ps;                        // alpha == 1 exactly
      }

      bf16x8 pf0 = *(const bf16x8*)(&Ps[(wv * 16 + c) * 72 + 8 * g]);
      bf16x8 pf1 = *(const bf16x8*)(&Ps[(wv * 16 + c) * 72 + 32 + 8 * g]);
#pragma unroll
      for (int nd = 0; nd < 8; ++nd) {
        bf16x8 vf0 = *(const bf16x8*)(&Vs[(16 * nd + c) * 72 + 8 * g]);
        bf16x8 vf1 = *(const bf16x8*)(&Vs[(16 * nd + c) * 72 + 32 + 8 * g]);
        acco[nd] = __builtin_amdgcn_mfma_f32_16x16x32_bf16(pf0, vf0, acco[nd], 0, 0, 0);
        acco[nd] = __builtin_amdgcn_mfma_f32_16x16x32_bf16(pf1, vf1, acco[nd], 0, 0, 0);
      }
      __syncthreads();

      if (more) {
#pragma unroll
        for (int j = 0; j < 8; ++j) {
          *(unsigned*)(&Vs[(vdb + j) * 72 + 2 * vkp]) =
              (unsigned)v0a[j] | ((unsigned)v1a[j] << 16);
          *(unsigned*)(&Vs[(vdb + 8 + j) * 72 + 2 * vkp]) =
              (unsigned)v0b[j] | ((unsigned)v1b[j] << 16);
        }
        __syncthreads();
      }
      cur = nxt;
    }

    const float inv = 1.f / l;
    float ir[4];
#pragma unroll
    for (int r = 0; r < 4; ++r) ir[r] = __shfl(inv, 4 * g + r);
#pragma unroll
    for (int r = 0; r < 4; ++r) {
      const long tok = (long)((b << 11) | (q0 + wv * 16 + 4 * g + r));
#pragma unroll
      for (int nd = 0; nd < 8; ++nd)
        ab16[tok * 2048 + hh * 128 + nd * 16 + c] = f2b(acco[nd][r] * ir[r]);
    }
  }
}

// ---------------------------------------------------------------------------
// Fused LayerNorm(a), LayerNorm(h), blend -> bf16 (inputs bf16).
// ---------------------------------------------------------------------------
__global__ __launch_bounds__(256)
void ln_blend(const u16* __restrict__ a, const u16* __restrict__ h,
              u16* __restrict__ ab,
              const float* __restrict__ gate,
              const float* __restrict__ ga, const float* __restrict__ ba,
              const float* __restrict__ gh, const float* __restrict__ bhv)
{
  const int tid = threadIdx.x;
  const long roff = (long)blockIdx.x * 2048 + tid * 8;
  float av[8], hv[8];
  {
    us8 ua = *(const us8*)(a + roff);
    us8 uh = *(const us8*)(h + roff);
#pragma unroll
    for (int i = 0; i < 8; ++i) { av[i] = b2f(ua[i]); hv[i] = b2f(uh[i]); }
  }
  float sa = 0.f, sa2 = 0.f, sh = 0.f, sh2 = 0.f;
#pragma unroll
  for (int i = 0; i < 8; ++i) {
    sa += av[i]; sa2 += av[i] * av[i];
    sh += hv[i]; sh2 += hv[i] * hv[i];
  }
#pragma unroll
  for (int o = 1; o < 64; o <<= 1) {
    sa += __shfl_xor(sa, o); sa2 += __shfl_xor(sa2, o);
    sh += __shfl_xor(sh, o); sh2 += __shfl_xor(sh2, o);
  }
  __shared__ float red[4][4];
  const int wv = tid >> 6;
  if ((tid & 63) == 0) { red[0][wv] = sa; red[1][wv] = sa2; red[2][wv] = sh; red[3][wv] = sh2; }
  __syncthreads();
  sa  = red[0][0] + red[0][1] + red[0][2] + red[0][3];
  sa2 = red[1][0] + red[1][1] + red[1][2] + red[1][3];
  sh  = red[2][0] + red[2][1] + red[2][2] + red[2][3];
  sh2 = red[3][0] + red[3][1] + red[3][2] + red[3][3];
  const float inv = 1.f / 2048.f;
  float ma = sa * inv,  va = sa2 * inv - ma * ma;
  float mh = sh * inv,  vh = sh2 * inv - mh * mh;
  float ra = rsqrtf(va + 1e-5f), rh = rsqrtf(vh + 1e-5f);
  float g = 1.f / (1.f + __expf(-gate[0]));
  g = fminf(fmaxf(g, 0.05f), 0.95f);
  const int j0 = tid * 8;
  us8 o;
#pragma unroll
  for (int i = 0; i < 8; ++i) {
    float aa = (av[i] - ma) * ra * ga[j0 + i] + ba[j0 + i];
    float hn = (hv[i] - mh) * rh * gh[j0 + i] + bhv[j0 + i];
    o[i] = f2b((1.f - g) * aa + g * hn);
  }
  *(us8*)(ab + roff) = o;
}

// ---------------------------------------------------------------------------
extern "C" void kernel_launch(void* const* d_in, const int* in_sizes, int n_in,
                              void* d_out, int out_size, void* d_ws, size_t ws_size,
                              hipStream_t stream)
{
  const float* x    = (const float*)d_in[0];
  const float* cosT = (const float*)d_in[1];
  const float* sinT = (const float*)d_in[2];
  const float* qkvw = (const float*)d_in[3];
  const float* outw = (const float*)d_in[4];
  const float* gate = (const float*)d_in[5];
  const float* ga   = (const float*)d_in[6];
  const float* ba   = (const float*)d_in[7];
  const float* gh   = (const float*)d_in[8];
  const float* bhv  = (const float*)d_in[9];
  float* out = (float*)d_out;

  char* w = (char*)d_ws;
  u16* qb   = (u16*)w;
  u16* kb   = (u16*)(w + (16u << 20));
  u16* vb   = (u16*)(w + (32u << 20));
  u16* xb   = (u16*)(w + (48u << 20));
  u16* ab16 = (u16*)(w + (48u << 20));
  u16* wb   = (u16*)(w + (64u << 20));
  u16* hb16 = (u16*)(w + (84u << 20));
  u16* Fm   = (u16*)(w + (100u << 20));
  u16* Cm   = (u16*)(w + (100u << 20) + 40960);
  u16* ob   = (u16*)(w + (104u << 20));
  u16* ab   = qb;

  convert_init<<<12440, 256, 0, stream>>>(x, qkvw, outw, xb, wb, ob, Fm, Cm);
  gemm_bf16<0><<<1536, 256, 0, stream>>>(xb, wb, nullptr, qb, kb, vb,
                                         cosT, sinT, 4096, 6144, 2048);
  flash_attn<<<dim3(32, 16), 256, 0, stream>>>(qb, kb, vb, ab16);
  holo_fused<<<512, 512, 0, stream>>>(qb, kb, vb, Fm, Cm, hb16);
  ln_blend<<<4096, 256, 0, stream>>>(ab16, hb16, ab, gate, ga, ba, gh, bhv);
  gemm_bf16<1><<<512, 256, 0, stream>>>(ab, ob, out, nullptr, nullptr, nullptr,
                                        nullptr, nullptr, 4096, 2048, 2048);
}

// Round 16
// 305.224 us; speedup vs baseline: 1.0208x; 1.0208x over previous
//
#include <hip/hip_runtime.h>

typedef unsigned short u16;
typedef __attribute__((ext_vector_type(4))) unsigned short us4;
typedef __attribute__((ext_vector_type(8))) unsigned short us8;
typedef __attribute__((ext_vector_type(8))) __bf16 bf16x8;
typedef __attribute__((ext_vector_type(4))) float f32x4;

#define L2E 1.4426950408889634f
#define RSQ128 0.08838834764831845f

__device__ __forceinline__ u16 f2b(float f) {
  unsigned u = __builtin_bit_cast(unsigned, f);
  u += 0x7fffu + ((u >> 16) & 1u);          // round-to-nearest-even
  return (u16)(u >> 16);
}
__device__ __forceinline__ float b2f(u16 s) {
  unsigned u = ((unsigned)s) << 16;
  return __builtin_bit_cast(float, u);
}

__device__ __forceinline__ void gload16(const u16* g, const u16* l) {
  __builtin_amdgcn_global_load_lds(
      (const __attribute__((address_space(1))) unsigned*)g,
      (__attribute__((address_space(3))) unsigned*)l, 16, 0, 0);
}

// ---------------------------------------------------------------------------
// Fused f32->bf16 convert for x, qkv_w, out_w AND DFT-table init, one launch.
// ---------------------------------------------------------------------------
__global__ __launch_bounds__(256)
void convert_init(const float* __restrict__ x, const float* __restrict__ w1,
                  const float* __restrict__ w2,
                  u16* __restrict__ dx, u16* __restrict__ dw1, u16* __restrict__ dw2,
                  u16* __restrict__ Fm, u16* __restrict__ Cm)
{
  const int bi = blockIdx.x;
  if (bi >= 12288) {
    const int i = (bi - 12288) * 256 + threadIdx.x;
    const float w0 = 6.283185307179586f / 128.f;
    if (i < 144 * 128) {
      const int fc = i >> 7, d = i & 127;
      float v = 0.f;
      if (fc < 130) {
        const int f = fc >> 1;
        const float ang = (float)((f * d) & 127) * w0;
        v = ((fc & 1) == 0 ? cosf(ang) : -sinf(ang)) * RSQ128;
      }
      Fm[i] = f2b(v);
    } else {
      const int j = i - 144 * 128;
      const int t = j / 160, fc = j % 160;
      float v = 0.f;
      if (fc < 130) {
        const int f = fc >> 1;
        if ((fc & 1) == 0) {
          if (f == 0)       v = RSQ128;
          else if (f == 64) v = (t & 1) ? -RSQ128 : RSQ128;
          else              v = 2.f * cosf((float)((f * t) & 127) * w0) * RSQ128;
        } else {
          if (f != 0 && f != 64)
            v = -2.f * sinf((float)((f * t) & 127) * w0) * RSQ128;
        }
      }
      Cm[j] = f2b(v);
    }
    return;
  }
  const float* src; u16* dst; long off;
  if (bi < 4096)        { src = x;  dst = dx;  off = (long)bi * 2048; }
  else if (bi < 10240)  { src = w1; dst = dw1; off = (long)(bi - 4096) * 2048; }
  else                  { src = w2; dst = dw2; off = (long)(bi - 10240) * 2048; }
  const long i = off + threadIdx.x * 8;
  float4 a = *(const float4*)(src + i);
  float4 b = *(const float4*)(src + i + 4);
  us8 o = { f2b(a.x), f2b(a.y), f2b(a.z), f2b(a.w),
            f2b(b.x), f2b(b.y), f2b(b.z), f2b(b.w) };
  *(us8*)(dst + i) = o;
}

// ---------------------------------------------------------------------------
// m97-structure bf16 TN GEMM, 16x16x32 MFMA, BK=64, L2-aware tile order
// (PROVEN rounds 9-14; round-15's 32x32 MFMA regressed via 4-way LDS
// conflicts within 32-lane issue phases -> reverted).
// MODE 0: RoPE + scatter to per-head q/k/v bf16. MODE 1: plain f32 store.
// ---------------------------------------------------------------------------
template<int MODE>
__global__ __launch_bounds__(256, 4)
void gemm_bf16(const u16* __restrict__ A, const u16* __restrict__ Bm,
               float* __restrict__ Cout,
               u16* __restrict__ qb, u16* __restrict__ kb, u16* __restrict__ vb,
               const float* __restrict__ cosT, const float* __restrict__ sinT,
               int M, int N, int K)
{
  __shared__ u16 As[128 * 64];
  __shared__ u16 Bs[128 * 64];
  const int tid  = threadIdx.x;
  const int lane = tid & 63;
  const int wid  = tid >> 6;
  const int c    = lane & 15;
  const int g    = lane >> 4;

  const int cpx  = gridDim.x >> 3;        // tiles per XCD
  const int ntx  = N >> 7;
  const int mpx  = cpx / ntx;             // m-panels per XCD
  const int xcd  = blockIdx.x & 7;
  const int t    = blockIdx.x >> 3;
  const int m0 = (xcd * mpx + (t % mpx)) * 128;
  const int n0 = (t / mpx) * 128;
  const int wm = (wid >> 1) * 64;
  const int wn = (wid & 1) * 64;

  f32x4 acc[4][4];
#pragma unroll
  for (int i = 0; i < 4; ++i)
#pragma unroll
    for (int j = 0; j < 4; ++j) acc[i][j] = (f32x4)0.f;

  const int sr8 = lane >> 3;
  const int scb = (lane & 7) ^ sr8;
  const u16* Ag = A  + (long)(m0 + wid * 32 + sr8) * K + scb * 8;
  const u16* Bg = Bm + (long)(n0 + wid * 32 + sr8) * K + scb * 8;

  for (int k0 = 0; k0 < K; k0 += 64) {
#pragma unroll
    for (int u = 0; u < 4; ++u) {
      gload16(Ag + (long)(u * 8) * K + k0, &As[(wid * 32 + u * 8) * 64]);
      gload16(Bg + (long)(u * 8) * K + k0, &Bs[(wid * 32 + u * 8) * 64]);
    }
    __syncthreads();
#pragma unroll
    for (int ks = 0; ks < 2; ++ks) {
      const int kk = (((ks * 4 + g) ^ (c & 7))) * 8;
      bf16x8 af[4], bfr[4];
#pragma unroll
      for (int mi = 0; mi < 4; ++mi)
        af[mi]  = *(const bf16x8*)(As + (wm + mi * 16 + c) * 64 + kk);
#pragma unroll
      for (int ni = 0; ni < 4; ++ni)
        bfr[ni] = *(const bf16x8*)(Bs + (wn + ni * 16 + c) * 64 + kk);
#pragma unroll
      for (int mi = 0; mi < 4; ++mi)
#pragma unroll
        for (int ni = 0; ni < 4; ++ni)
          acc[mi][ni] = __builtin_amdgcn_mfma_f32_16x16x32_bf16(af[mi], bfr[ni], acc[mi][ni], 0, 0, 0);
    }
    __syncthreads();
  }

  if (MODE == 0) {
    const int w  = n0 >> 11;
    const int hh = (n0 >> 7) & 15;
#pragma unroll
    for (int mi = 0; mi < 4; ++mi) {
      const int rowb = m0 + wm + mi * 16 + g * 4;
#pragma unroll
      for (int ni = 0; ni < 4; ++ni) {
        const int d = wn + ni * 16 + c;
#pragma unroll
        for (int r = 0; r < 4; ++r) {
          float val = acc[mi][ni][r];
          float oth = __shfl_xor(val, 1);
          const int tok = rowb + r;
          const int s   = tok & 2047;
          const long idx = ((long)(((tok >> 11) << 4) | hh) * 2048 + s) * 128 + d;
          if (w == 2) {
            vb[idx] = f2b(val);
          } else {
            float cc = cosT[s * 64 + (d >> 1)];
            float sn = sinT[s * 64 + (d >> 1)];
            float res = (d & 1) ? (oth * sn + val * cc) : (val * cc - oth * sn);
            ((w == 0) ? qb : kb)[idx] = f2b(res);
          }
        }
      }
    }
  } else {
#pragma unroll
    for (int mi = 0; mi < 4; ++mi) {
      const int rowb = m0 + wm + mi * 16 + g * 4;
#pragma unroll
      for (int ni = 0; ni < 4; ++ni) {
        const int col = n0 + wn + ni * 16 + c;
#pragma unroll
        for (int r = 0; r < 4; ++r)
          Cout[(long)(rowb + r) * N + col] = acc[mi][ni][r];
      }
    }
  }
}

// ---------------------------------------------------------------------------
// FUSED holographic path (proven round 12).
// ---------------------------------------------------------------------------
__global__ __launch_bounds__(512, 1)
void holo_fused(const u16* __restrict__ qb, const u16* __restrict__ kb,
                const u16* __restrict__ vb, const u16* __restrict__ Fm,
                const u16* __restrict__ Cm, u16* __restrict__ hb16)
{
  __shared__ u16 Cs[128 * 168];
  __shared__ u16 Un[128 * 168];
  u16* const Fs = Un;
  u16* const Ps = Un;
  const int tid = threadIdx.x, lane = tid & 63, wv = tid >> 6;
  const int c = lane & 15, g = lane >> 4;
  const long row0 = (long)blockIdx.x * 128;

  for (int i = tid; i < 144 * 16; i += 512) {
    const int fc = i >> 4, d8 = (i & 15) << 3;
    us8 v = *(const us8*)(Fm + fc * 128 + d8);
    *(us8*)((char*)Fs + ((fc * 256 + d8 * 2) ^ ((fc & 7) << 4))) = v;
  }
  for (int i = tid; i < 128 * 20; i += 512) {
    const int tr = i / 20, c8 = (i % 20) * 8;
    *(us8*)(Cs + tr * 168 + c8) = *(const us8*)(Cm + tr * 160 + c8);
  }

  const long ar = row0 + wv * 16 + c;
  bf16x8 aq[4], ak[4], av[4];
#pragma unroll
  for (int ks = 0; ks < 4; ++ks) {
    aq[ks] = *(const bf16x8*)(qb + ar * 128 + 32 * ks + 8 * g);
    ak[ks] = *(const bf16x8*)(kb + ar * 128 + 32 * ks + 8 * g);
    av[ks] = *(const bf16x8*)(vb + ar * 128 + 32 * ks + 8 * g);
  }
  __syncthreads();

  f32x4 accq[9], acck[9], accv[9];
#pragma unroll
  for (int nt = 0; nt < 9; ++nt) {
    accq[nt] = (f32x4)0.f; acck[nt] = (f32x4)0.f; accv[nt] = (f32x4)0.f;
  }
#pragma unroll
  for (int nt = 0; nt < 9; ++nt) {
    const int fc = nt * 16 + c;
    const int sw = (fc & 7) << 4;
#pragma unroll
    for (int ks = 0; ks < 4; ++ks) {
      bf16x8 bf = *(const bf16x8*)((char*)Fs + ((fc * 256 + (32 * ks + 8 * g) * 2) ^ sw));
      accq[nt] = __builtin_amdgcn_mfma_f32_16x16x32_bf16(aq[ks], bf, accq[nt], 0, 0, 0);
      acck[nt] = __builtin_amdgcn_mfma_f32_16x16x32_bf16(ak[ks], bf, acck[nt], 0, 0, 0);
      accv[nt] = __builtin_amdgcn_mfma_f32_16x16x32_bf16(av[ks], bf, accv[nt], 0, 0, 0);
    }
  }
  __syncthreads();

  const bool even = ((c & 1) == 0);
  const int lr = wv * 16 + 4 * g;
#pragma unroll
  for (int nt = 0; nt < 9; ++nt) {
#pragma unroll
    for (int r = 0; r < 4; ++r) {
      float q = accq[nt][r], k = acck[nt][r], v = accv[nt][r];
      float xq = __shfl_xor(q, 1), xk = __shfl_xor(k, 1), xv = __shfl_xor(v, 1);
      float bc = even ? (k * v - xk * xv) : (xk * v + k * xv);
      float xbc = __shfl_xor(bc, 1);
      float p = even ? (q * bc + xq * xbc) : (xq * bc - q * xbc);
      Ps[(lr + r) * 168 + nt * 16 + c] = f2b(p);
    }
  }
  {
    const int zr = tid >> 2, zc = 144 + (tid & 3) * 4;
    us4 z = {0, 0, 0, 0};
    *(us4*)(Ps + zr * 168 + zc) = z;
  }
  __syncthreads();

  f32x4 acc2[8];
#pragma unroll
  for (int i = 0; i < 8; ++i) acc2[i] = (f32x4)0.f;
#pragma unroll
  for (int ks = 0; ks < 5; ++ks) {
    bf16x8 pa = *(const bf16x8*)(Ps + (wv * 16 + c) * 168 + ks * 32 + 8 * g);
#pragma unroll
    for (int nt2 = 0; nt2 < 8; ++nt2) {
      bf16x8 cb = *(const bf16x8*)(Cs + (nt2 * 16 + c) * 168 + ks * 32 + 8 * g);
      acc2[nt2] = __builtin_amdgcn_mfma_f32_16x16x32_bf16(pa, cb, acc2[nt2], 0, 0, 0);
    }
  }
#pragma unroll
  for (int nt2 = 0; nt2 < 8; ++nt2) {
#pragma unroll
    for (int r = 0; r < 4; ++r) {
      const int row = (int)row0 + wv * 16 + 4 * g + r;
      const int bh = row >> 11, s = row & 2047;
      const long addr = ((long)(((bh >> 4) << 11) | s) << 11) + ((bh & 15) << 7) + nt2 * 16 + c;
      hb16[addr] = f2b(acc2[nt2][r]);
    }
  }
}

// ---------------------------------------------------------------------------
// Causal flash attention v6 + defer-max (proven round 12) + T5 setprio
// around the MFMA clusters (2 independent blocks/CU at different phases ->
// the regime where setprio measured +4-7% on attn; pure scheduler hint).
// ---------------------------------------------------------------------------
__global__ __launch_bounds__(256, 2)
void flash_attn(const u16* __restrict__ qb, const u16* __restrict__ kb,
                const u16* __restrict__ vb, u16* __restrict__ ab16)
{
  __shared__ u16 Ks[2][64 * 128];
  __shared__ u16 Vs[128 * 72];
  __shared__ u16 Ps[64 * 72];
  const int tid  = threadIdx.x;
  const int lane = tid & 63;
  const int wv   = tid >> 6;      // 0..3
  const int c    = lane & 15;
  const int g    = lane >> 4;
  const int bh = blockIdx.x;
  const int zz = blockIdx.y;      // 0..15
  const long basek = (long)bh * 2048 * 128;
  const int b = bh >> 4, hh = bh & 15;
  const u16* kbb = kb + basek;
  const u16* vbb = vb + basek;

  int kr[4], kc[4];
#pragma unroll
  for (int u = 0; u < 4; ++u) {
    kr[u] = 16 * u + 4 * wv + (lane >> 4);
    kc[u] = ((lane & 15) ^ (kr[u] & 7)) * 8;
  }
  const int vkp = tid & 31;
  const int vdb = (tid >> 5) * 16;

  for (int ph = 0; ph < 2; ++ph) {
    const int qt = ph ? (31 - zz) : zz;
    const int q0 = qt * 64;

    bf16x8 qf[4];
    {
      const u16* qptr = qb + basek + (long)(q0 + wv * 16 + c) * 128 + 8 * g;
#pragma unroll
      for (int ks = 0; ks < 4; ++ks) qf[ks] = *(const bf16x8*)(qptr + 32 * ks);
    }
    f32x4 acco[8];
#pragma unroll
    for (int i = 0; i < 8; ++i) acco[i] = (f32x4)0.f;
    float m = -1e30f, l = 0.f;

    {
#pragma unroll
      for (int u = 0; u < 4; ++u)
        gload16(kbb + (long)kr[u] * 128 + kc[u], &Ks[0][(16 * u + 4 * wv) * 128]);
      const u16* vp = vbb + (long)(2 * vkp) * 128 + vdb;
      us8 v0a = *(const us8*)vp;
      us8 v0b = *(const us8*)(vp + 8);
      us8 v1a = *(const us8*)(vp + 128);
      us8 v1b = *(const us8*)(vp + 136);
      __syncthreads();
#pragma unroll
      for (int j = 0; j < 8; ++j) {
        *(unsigned*)(&Vs[(vdb + j) * 72 + 2 * vkp]) =
            (unsigned)v0a[j] | ((unsigned)v1a[j] << 16);
        *(unsigned*)(&Vs[(vdb + 8 + j) * 72 + 2 * vkp]) =
            (unsigned)v0b[j] | ((unsigned)v1b[j] << 16);
      }
      __syncthreads();
    }

    int cur = 0;
    for (int t = 0; t <= qt; ++t) {
      const int nxt = cur ^ 1;
      const bool more = (t < qt);
      us8 v0a, v0b, v1a, v1b;
      if (more) {
        const int kv1 = (t + 1) * 64;
#pragma unroll
        for (int u = 0; u < 4; ++u)
          gload16(kbb + (long)(kv1 + kr[u]) * 128 + kc[u],
                  &Ks[nxt][(16 * u + 4 * wv) * 128]);
        const u16* vp = vbb + (long)(kv1 + 2 * vkp) * 128 + vdb;
        v0a = *(const us8*)vp;
        v0b = *(const us8*)(vp + 8);
        v1a = *(const us8*)(vp + 128);
        v1b = *(const us8*)(vp + 136);
      }

      const int kv0 = t * 64;
      f32x4 accs[4];
#pragma unroll
      for (int i = 0; i < 4; ++i) accs[i] = (f32x4)0.f;
      __builtin_amdgcn_s_setprio(1);
#pragma unroll
      for (int ni = 0; ni < 4; ++ni) {
        const int krow = ni * 16 + c;
#pragma unroll
        for (int ks = 0; ks < 4; ++ks) {
          bf16x8 kf = *(const bf16x8*)(&Ks[cur][krow * 128 + (((4 * ks + g) ^ (krow & 7)) * 8)]);
          accs[ni] = __builtin_amdgcn_mfma_f32_16x16x32_bf16(kf, qf[ks], accs[ni], 0, 0, 0);
        }
      }
      __builtin_amdgcn_s_setprio(0);

      const int qrow = q0 + wv * 16 + c;
      float sv[4][4];
      float tmax = -1e30f;
      const bool maskt = (t == qt);
#pragma unroll
      for (int ni = 0; ni < 4; ++ni)
#pragma unroll
        for (int r = 0; r < 4; ++r) {
          float s = accs[ni][r] * RSQ128;
          if (maskt && (kv0 + ni * 16 + 4 * g + r > qrow)) s = -1e30f;
          sv[ni][r] = s;
          tmax = fmaxf(tmax, s);
        }
      tmax = fmaxf(tmax, __shfl_xor(tmax, 16));
      tmax = fmaxf(tmax, __shfl_xor(tmax, 32));
      const bool needr = !__all(tmax <= m);
      const float mn = needr ? fmaxf(m, tmax) : m;
      float ps = 0.f;
#pragma unroll
      for (int ni = 0; ni < 4; ++ni) {
        us4 pk;
#pragma unroll
        for (int r = 0; r < 4; ++r) {
          float p = exp2f((sv[ni][r] - mn) * L2E);
          ps += p;
          pk[r] = f2b(p);
        }
        *(us4*)(&Ps[(wv * 16 + c) * 72 + ni * 16 + 4 * g]) = pk;
      }
      ps += __shfl_xor(ps, 16);
      ps += __shfl_xor(ps, 32);
      if (needr) {                      // wave-uniform branch
        const float alpha = exp2f((m - mn) * L2E);
        m = mn;
        l = l * alpha + ps;
        float ar[4];
#pragma unroll
        for (int r = 0; r < 4; ++r) ar[r] = __shfl(alpha, 4 * g + r);
#pragma unroll
        for (int i = 0; i < 8; ++i)
#pragma unroll
          for (int r = 0; r < 4; ++r) acco[i][r] *= ar[r];
      } else {
        l += ps;                        // alpha == 1 exactly
      }

      bf16x8 pf0 = *(const bf16x8*)(&Ps[(wv * 16 + c) * 72 + 8 * g]);
      bf16x8 pf1 = *(const bf16x8*)(&Ps[(wv * 16 + c) * 72 + 32 + 8 * g]);
      __builtin_amdgcn_s_setprio(1);
#pragma unroll
      for (int nd = 0; nd < 8; ++nd) {
        bf16x8 vf0 = *(const bf16x8*)(&Vs[(16 * nd + c) * 72 + 8 * g]);
        bf16x8 vf1 = *(const bf16x8*)(&Vs[(16 * nd + c) * 72 + 32 + 8 * g]);
        acco[nd] = __builtin_amdgcn_mfma_f32_16x16x32_bf16(pf0, vf0, acco[nd], 0, 0, 0);
        acco[nd] = __builtin_amdgcn_mfma_f32_16x16x32_bf16(pf1, vf1, acco[nd], 0, 0, 0);
      }
      __builtin_amdgcn_s_setprio(0);
      __syncthreads();

      if (more) {
#pragma unroll
        for (int j = 0; j < 8; ++j) {
          *(unsigned*)(&Vs[(vdb + j) * 72 + 2 * vkp]) =
              (unsigned)v0a[j] | ((unsigned)v1a[j] << 16);
          *(unsigned*)(&Vs[(vdb + 8 + j) * 72 + 2 * vkp]) =
              (unsigned)v0b[j] | ((unsigned)v1b[j] << 16);
        }
        __syncthreads();
      }
      cur = nxt;
    }

    const float inv = 1.f / l;
    float ir[4];
#pragma unroll
    for (int r = 0; r < 4; ++r) ir[r] = __shfl(inv, 4 * g + r);
#pragma unroll
    for (int r = 0; r < 4; ++r) {
      const long tok = (long)((b << 11) | (q0 + wv * 16 + 4 * g + r));
#pragma unroll
      for (int nd = 0; nd < 8; ++nd)
        ab16[tok * 2048 + hh * 128 + nd * 16 + c] = f2b(acco[nd][r] * ir[r]);
    }
  }
}

// ---------------------------------------------------------------------------
// Fused LayerNorm(a), LayerNorm(h), blend -> bf16 (inputs bf16).
// ---------------------------------------------------------------------------
__global__ __launch_bounds__(256)
void ln_blend(const u16* __restrict__ a, const u16* __restrict__ h,
              u16* __restrict__ ab,
              const float* __restrict__ gate,
              const float* __restrict__ ga, const float* __restrict__ ba,
              const float* __restrict__ gh, const float* __restrict__ bhv)
{
  const int tid = threadIdx.x;
  const long roff = (long)blockIdx.x * 2048 + tid * 8;
  float av[8], hv[8];
  {
    us8 ua = *(const us8*)(a + roff);
    us8 uh = *(const us8*)(h + roff);
#pragma unroll
    for (int i = 0; i < 8; ++i) { av[i] = b2f(ua[i]); hv[i] = b2f(uh[i]); }
  }
  float sa = 0.f, sa2 = 0.f, sh = 0.f, sh2 = 0.f;
#pragma unroll
  for (int i = 0; i < 8; ++i) {
    sa += av[i]; sa2 += av[i] * av[i];
    sh += hv[i]; sh2 += hv[i] * hv[i];
  }
#pragma unroll
  for (int o = 1; o < 64; o <<= 1) {
    sa += __shfl_xor(sa, o); sa2 += __shfl_xor(sa2, o);
    sh += __shfl_xor(sh, o); sh2 += __shfl_xor(sh2, o);
  }
  __shared__ float red[4][4];
  const int wv = tid >> 6;
  if ((tid & 63) == 0) { red[0][wv] = sa; red[1][wv] = sa2; red[2][wv] = sh; red[3][wv] = sh2; }
  __syncthreads();
  sa  = red[0][0] + red[0][1] + red[0][2] + red[0][3];
  sa2 = red[1][0] + red[1][1] + red[1][2] + red[1][3];
  sh  = red[2][0] + red[2][1] + red[2][2] + red[2][3];
  sh2 = red[3][0] + red[3][1] + red[3][2] + red[3][3];
  const float inv = 1.f / 2048.f;
  float ma = sa * inv,  va = sa2 * inv - ma * ma;
  float mh = sh * inv,  vh = sh2 * inv - mh * mh;
  float ra = rsqrtf(va + 1e-5f), rh = rsqrtf(vh + 1e-5f);
  float g = 1.f / (1.f + __expf(-gate[0]));
  g = fminf(fmaxf(g, 0.05f), 0.95f);
  const int j0 = tid * 8;
  us8 o;
#pragma unroll
  for (int i = 0; i < 8; ++i) {
    float aa = (av[i] - ma) * ra * ga[j0 + i] + ba[j0 + i];
    float hn = (hv[i] - mh) * rh * gh[j0 + i] + bhv[j0 + i];
    o[i] = f2b((1.f - g) * aa + g * hn);
  }
  *(us8*)(ab + roff) = o;
}

// ---------------------------------------------------------------------------
extern "C" void kernel_launch(void* const* d_in, const int* in_sizes, int n_in,
                              void* d_out, int out_size, void* d_ws, size_t ws_size,
                              hipStream_t stream)
{
  const float* x    = (const float*)d_in[0];
  const float* cosT = (const float*)d_in[1];
  const float* sinT = (const float*)d_in[2];
  const float* qkvw = (const float*)d_in[3];
  const float* outw = (const float*)d_in[4];
  const float* gate = (const float*)d_in[5];
  const float* ga   = (const float*)d_in[6];
  const float* ba   = (const float*)d_in[7];
  const float* gh   = (const float*)d_in[8];
  const float* bhv  = (const float*)d_in[9];
  float* out = (float*)d_out;

  char* w = (char*)d_ws;
  u16* qb   = (u16*)w;
  u16* kb   = (u16*)(w + (16u << 20));
  u16* vb   = (u16*)(w + (32u << 20));
  u16* xb   = (u16*)(w + (48u << 20));
  u16* ab16 = (u16*)(w + (48u << 20));
  u16* wb   = (u16*)(w + (64u << 20));
  u16* hb16 = (u16*)(w + (84u << 20));
  u16* Fm   = (u16*)(w + (100u << 20));
  u16* Cm   = (u16*)(w + (100u << 20) + 40960);
  u16* ob   = (u16*)(w + (104u << 20));
  u16* ab   = qb;

  convert_init<<<12440, 256, 0, stream>>>(x, qkvw, outw, xb, wb, ob, Fm, Cm);
  gemm_bf16<0><<<1536, 256, 0, stream>>>(xb, wb, nullptr, qb, kb, vb,
                                         cosT, sinT, 4096, 6144, 2048);
  flash_attn<<<dim3(32, 16), 256, 0, stream>>>(qb, kb, vb, ab16);
  holo_fused<<<512, 512, 0, stream>>>(qb, kb, vb, Fm, Cm, hb16);
  ln_blend<<<4096, 256, 0, stream>>>(ab16, hb16, ab, gate, ga, ba, gh, bhv);
  gemm_bf16<1><<<512, 256, 0, stream>>>(ab, ob, out, nullptr, nullptr, nullptr,
                                        nullptr, nullptr, 4096, 2048, 2048);
}